// Round 1
// baseline (1488.252 us; speedup 1.0000x reference)
//
#include <hip/hip_runtime.h>

#define BB 2
#define NN 32768
#define EN 32768   // edges per batch

// ---------------------------------------------------------------------------
// helpers
// ---------------------------------------------------------------------------
__device__ __forceinline__ void load16(float* dst, const float* __restrict__ src) {
    const float4* p = reinterpret_cast<const float4*>(src);
    #pragma unroll
    for (int i = 0; i < 4; ++i) {
        float4 v = p[i];
        dst[4*i+0] = v.x; dst[4*i+1] = v.y; dst[4*i+2] = v.z; dst[4*i+3] = v.w;
    }
}

__device__ __forceinline__ void store16(float* __restrict__ dst, const float* src) {
    float4* p = reinterpret_cast<float4*>(dst);
    #pragma unroll
    for (int i = 0; i < 4; ++i) {
        float4 v;
        v.x = src[4*i+0]; v.y = src[4*i+1]; v.z = src[4*i+2]; v.w = src[4*i+3];
        p[i] = v;
    }
}

__device__ __forceinline__ void layernorm32(float* h,
                                            const float* __restrict__ g,
                                            const float* __restrict__ b) {
    float m = 0.f;
    #pragma unroll
    for (int j = 0; j < 32; ++j) m += h[j];
    m *= (1.f / 32.f);
    float v = 0.f;
    #pragma unroll
    for (int j = 0; j < 32; ++j) { float d = h[j] - m; v = fmaf(d, d, v); }
    v *= (1.f / 32.f);
    const float r = rsqrtf(v + 1e-5f);
    #pragma unroll
    for (int j = 0; j < 32; ++j) h[j] = fmaf((h[j] - m) * r, g[j], b[j]);
}

// Deep MLP: din -> 32, then 32 layers of 32->32, then 32 -> dout.
// relu after every matmul; optional LN after each relu (except the output).
// All weight/bias addresses are wave-uniform -> compiler emits scalar loads.
template<int DIN, int DOUT, bool HAS_LN>
__device__ __forceinline__ void mlp_run(
    const float* x,
    const float* __restrict__ Win,  const float* __restrict__ bin,
    const float* __restrict__ Wh,   const float* __restrict__ bh,
    const float* __restrict__ Wout, const float* __restrict__ bout,
    const float* __restrict__ lng,  const float* __restrict__ lnb,
    float* out)
{
    float h[32];
    #pragma unroll
    for (int j = 0; j < 32; ++j) h[j] = bin[j];
    #pragma unroll
    for (int k = 0; k < DIN; ++k) {
        const float xk = x[k];
        #pragma unroll
        for (int j = 0; j < 32; ++j) h[j] = fmaf(xk, Win[k*32 + j], h[j]);
    }
    #pragma unroll
    for (int j = 0; j < 32; ++j) h[j] = fmaxf(h[j], 0.f);
    if (HAS_LN) layernorm32(h, lng, lnb);

    // 32 hidden layers; keep outer loop rolled (code size), inner 1024 FMAs
    // fully unrolled (32 independent acc chains, weights from SGPRs).
    #pragma unroll 1
    for (int l = 0; l < 32; ++l) {
        const float* __restrict__ W  = Wh + l*1024;
        const float* __restrict__ bl = bh + l*32;
        float hn[32];
        #pragma unroll
        for (int j = 0; j < 32; ++j) hn[j] = bl[j];
        #pragma unroll
        for (int k = 0; k < 32; ++k) {
            const float hk = h[k];
            #pragma unroll
            for (int j = 0; j < 32; ++j) hn[j] = fmaf(hk, W[k*32 + j], hn[j]);
        }
        #pragma unroll
        for (int j = 0; j < 32; ++j) h[j] = fmaxf(hn[j], 0.f);
        if (HAS_LN) layernorm32(h, lng + (l+1)*32, lnb + (l+1)*32);
    }

    #pragma unroll
    for (int j = 0; j < DOUT; ++j) {
        float acc = bout[j];
        #pragma unroll
        for (int k = 0; k < 32; ++k) acc = fmaf(h[k], Wout[k*DOUT + j], acc);
        out[j] = fmaxf(acc, 0.f);
    }
}

// ---------------------------------------------------------------------------
// kernels
// ---------------------------------------------------------------------------
__global__ __launch_bounds__(256) void node_encode_kernel(
    const float* __restrict__ nodes, const float* __restrict__ gvec,
    const float* __restrict__ Win,  const float* __restrict__ bin,
    const float* __restrict__ Wh,   const float* __restrict__ bh,
    const float* __restrict__ Wout, const float* __restrict__ bout,
    float* __restrict__ ve)
{
    const int idx = blockIdx.x * blockDim.x + threadIdx.x;
    if (idx >= BB * NN) return;
    const int b = idx >> 15;   // / NN
    float x[7];
    #pragma unroll
    for (int i = 0; i < 6; ++i) x[i] = nodes[(size_t)idx * 6 + i];
    x[6] = gvec[b];
    float o[16];
    mlp_run<7, 16, false>(x, Win, bin, Wh, bh, Wout, bout, nullptr, nullptr, o);
    store16(ve + (size_t)idx * 16, o);
}

__global__ __launch_bounds__(256) void edge_encode_kernel(
    const float* __restrict__ nodes, const float* __restrict__ edges,
    const int* __restrict__ senders, const int* __restrict__ receivers,
    const float* __restrict__ Win,  const float* __restrict__ bin,
    const float* __restrict__ Wh,   const float* __restrict__ bh,
    const float* __restrict__ Wout, const float* __restrict__ bout,
    float* __restrict__ ee)
{
    const int idx = blockIdx.x * blockDim.x + threadIdx.x;
    if (idx >= BB * EN) return;
    const int b = idx >> 15;   // / EN
    const int s = senders[idx];
    const int r = receivers[idx];
    const float* ps = nodes + ((size_t)b * NN + s) * 6;   // pos = first 3 node feats
    const float* pr = nodes + ((size_t)b * NN + r) * 6;
    float rel0 = ps[0] - pr[0];
    float rel1 = ps[1] - pr[1];
    float rel2 = ps[2] - pr[2];
    float nrm = sqrtf(rel0*rel0 + rel1*rel1 + rel2*rel2);
    float x[5] = { edges[idx], rel0, rel1, rel2, nrm };
    float o[16];
    mlp_run<5, 16, false>(x, Win, bin, Wh, bh, Wout, bout, nullptr, nullptr, o);
    store16(ee + (size_t)idx * 16, o);
}

__global__ __launch_bounds__(256) void edge_update_kernel(
    const float* __restrict__ gvec,
    const int* __restrict__ senders, const int* __restrict__ receivers,
    const float* __restrict__ ve, float* __restrict__ ee, float* __restrict__ agg,
    const float* __restrict__ Win,  const float* __restrict__ bin,
    const float* __restrict__ Wh,   const float* __restrict__ bh,
    const float* __restrict__ Wout, const float* __restrict__ bout,
    const float* __restrict__ lng,  const float* __restrict__ lnb)
{
    const int idx = blockIdx.x * blockDim.x + threadIdx.x;
    if (idx >= BB * EN) return;
    const int b = idx >> 15;
    const int s = senders[idx];
    const int r = receivers[idx];
    float x[49];
    load16(x +  0, ee + (size_t)idx * 16);
    load16(x + 16, ve + ((size_t)b * NN + s) * 16);
    load16(x + 32, ve + ((size_t)b * NN + r) * 16);
    x[48] = gvec[b];
    float o[16];
    mlp_run<49, 16, true>(x, Win, bin, Wh, bh, Wout, bout, lng, lnb, o);
    store16(ee + (size_t)idx * 16, o);
    float* ap = agg + ((size_t)b * NN + r) * 16;
    #pragma unroll
    for (int j = 0; j < 16; ++j) atomicAdd(ap + j, o[j]);
}

__global__ __launch_bounds__(256) void node_update_kernel(
    const float* __restrict__ gvec,
    const float* __restrict__ agg, float* __restrict__ ve,
    const float* __restrict__ Win,  const float* __restrict__ bin,
    const float* __restrict__ Wh,   const float* __restrict__ bh,
    const float* __restrict__ Wout, const float* __restrict__ bout,
    const float* __restrict__ lng,  const float* __restrict__ lnb)
{
    const int idx = blockIdx.x * blockDim.x + threadIdx.x;
    if (idx >= BB * NN) return;
    const int b = idx >> 15;
    float x[33];
    load16(x +  0, agg + (size_t)idx * 16);
    load16(x + 16, ve  + (size_t)idx * 16);
    x[32] = gvec[b];
    float o[16];
    mlp_run<33, 16, true>(x, Win, bin, Wh, bh, Wout, bout, lng, lnb, o);
    store16(ve + (size_t)idx * 16, o);
}

__global__ __launch_bounds__(256) void decode_kernel(
    const float* __restrict__ ve,
    const float* __restrict__ Win,  const float* __restrict__ bin,
    const float* __restrict__ Wh,   const float* __restrict__ bh,
    const float* __restrict__ Wout, const float* __restrict__ bout,
    float* __restrict__ out)
{
    const int idx = blockIdx.x * blockDim.x + threadIdx.x;
    if (idx >= BB * NN) return;
    float x[16];
    load16(x, ve + (size_t)idx * 16);
    float o[3];
    mlp_run<16, 3, false>(x, Win, bin, Wh, bh, Wout, bout, nullptr, nullptr, o);
    out[(size_t)idx*3 + 0] = o[0];
    out[(size_t)idx*3 + 1] = o[1];
    out[(size_t)idx*3 + 2] = o[2];
}

// ---------------------------------------------------------------------------
// launch
// ---------------------------------------------------------------------------
extern "C" void kernel_launch(void* const* d_in, const int* in_sizes, int n_in,
                              void* d_out, int out_size, void* d_ws, size_t ws_size,
                              hipStream_t stream)
{
    const float* nodes     = (const float*)d_in[0];
    const float* edges     = (const float*)d_in[1];
    const float* gvec      = (const float*)d_in[2];
    const int*   senders   = (const int*)  d_in[3];
    const int*   receivers = (const int*)  d_in[4];

    const float* ne_Win  = (const float*)d_in[5];
    const float* ne_bin  = (const float*)d_in[6];
    const float* ne_Wh   = (const float*)d_in[7];
    const float* ne_bh   = (const float*)d_in[8];
    const float* ne_Wout = (const float*)d_in[9];
    const float* ne_bout = (const float*)d_in[10];

    const float* ed_Win  = (const float*)d_in[11];
    const float* ed_bin  = (const float*)d_in[12];
    const float* ed_Wh   = (const float*)d_in[13];
    const float* ed_bh   = (const float*)d_in[14];
    const float* ed_Wout = (const float*)d_in[15];
    const float* ed_bout = (const float*)d_in[16];

    const float* pe_Win  = (const float*)d_in[17];
    const float* pe_bin  = (const float*)d_in[18];
    const float* pe_Wh   = (const float*)d_in[19];
    const float* pe_bh   = (const float*)d_in[20];
    const float* pe_Wout = (const float*)d_in[21];
    const float* pe_bout = (const float*)d_in[22];
    const float* pe_lng  = (const float*)d_in[23];
    const float* pe_lnb  = (const float*)d_in[24];

    const float* pv_Win  = (const float*)d_in[25];
    const float* pv_bin  = (const float*)d_in[26];
    const float* pv_Wh   = (const float*)d_in[27];
    const float* pv_bh   = (const float*)d_in[28];
    const float* pv_Wout = (const float*)d_in[29];
    const float* pv_bout = (const float*)d_in[30];
    const float* pv_lng  = (const float*)d_in[31];
    const float* pv_lnb  = (const float*)d_in[32];

    const float* de_Win  = (const float*)d_in[33];
    const float* de_bin  = (const float*)d_in[34];
    const float* de_Wh   = (const float*)d_in[35];
    const float* de_bh   = (const float*)d_in[36];
    const float* de_Wout = (const float*)d_in[37];
    const float* de_bout = (const float*)d_in[38];

    // workspace layout (floats): ve | ee | agg  (1 Mi floats = 4 MB each)
    float* ve  = (float*)d_ws;
    float* ee  = ve + (size_t)BB * NN * 16;
    float* agg = ee + (size_t)BB * EN * 16;

    const dim3 blk(256);
    const dim3 grd((BB * NN + 255) / 256);

    node_encode_kernel<<<grd, blk, 0, stream>>>(nodes, gvec,
        ne_Win, ne_bin, ne_Wh, ne_bh, ne_Wout, ne_bout, ve);

    edge_encode_kernel<<<grd, blk, 0, stream>>>(nodes, edges, senders, receivers,
        ed_Win, ed_bin, ed_Wh, ed_bh, ed_Wout, ed_bout, ee);

    for (int step = 0; step < 2; ++step) {
        hipMemsetAsync(agg, 0, (size_t)BB * NN * 16 * sizeof(float), stream);
        edge_update_kernel<<<grd, blk, 0, stream>>>(gvec, senders, receivers,
            ve, ee, agg,
            pe_Win, pe_bin, pe_Wh, pe_bh, pe_Wout, pe_bout, pe_lng, pe_lnb);
        node_update_kernel<<<grd, blk, 0, stream>>>(gvec, agg, ve,
            pv_Win, pv_bin, pv_Wh, pv_bh, pv_Wout, pv_bout, pv_lng, pv_lnb);
    }

    decode_kernel<<<grd, blk, 0, stream>>>(ve,
        de_Win, de_bin, de_Wh, de_bh, de_Wout, de_bout, (float*)d_out);
}